// Round 1
// 708.747 us; speedup vs baseline: 1.1947x; 1.1947x over previous
//
#include <hip/hip_runtime.h>

// ForwardDecoder R3: latency-bound fix.
//   R2 counters: VALUBusy 7.2%, HBM 4.8%, Occupancy 1.5%, VGPR=76.
//   VGPR=76 proves the compiler collapsed R2's 96-reg double-buffer: staging
//   loads were sunk to just-before-use, exposing ~12 memory round-trips/row
//   (~4000 of the ~4900 cy/row). Fixes:
//   (1) Prefetch pipeline the compiler can't collapse: inline-asm
//       global_load_dwordx4 into 4 rotating register sets (distance = 2 rows,
//       24 loads in flight), manual s_waitcnt vmcnt(12) + sched_barrier(0)
//       fences (rule #18: fence needed so consumers can't hoist past the wait).
//   (2) All __shfl_up (ds_permute, ~40-100cy each at 1 wave/CU) replaced by
//       DPP: wave_shr1 (0x138) for +1 shifts; row_shr:1/2/4/8 + row_bcast15/31
//       (classic GCN scan network) for the 64-lane log-affine scan.

#define NEG_INF -1.0e8f

constexpr int Nr = 256;   // rows (N)
constexpr int Mc = 256;   // cols (M)

typedef float v4f __attribute__((ext_vector_type(4)));

__device__ __forceinline__ float lae2(float x, float y) {
    float m = fmaxf(x, y);
    float d = fminf(x, y) - m;            // <= 0, exp safe
    return m + __logf(1.0f + __expf(d));
}

__device__ __forceinline__ float lse3(float x0, float x1, float x2) {
    float m = fmaxf(x0, fmaxf(x1, x2));
    return m + __logf(__expf(x0 - m) + __expf(x1 - m) + __expf(x2 - m));
}

// DPP lane move: dst = src from pattern CTRL; invalid lanes keep own value
// (all uses are predicated or boundary-overwritten).
template <int CTRL>
__device__ __forceinline__ float dppf(float x) {
    int xi = __builtin_bit_cast(int, x);
    int ri = __builtin_amdgcn_update_dpp(xi, xi, CTRL, 0xF, 0xF, false);
    return __builtin_bit_cast(float, ri);
}
// DPP ctrl codes (gfx9/CDNA encoding):
//   0x110+d = row_shr:d   0x138 = wave_shr1   0x142 = row_bcast15   0x143 = row_bcast31

struct RowRegs { v4f t0, t1, t2, a0, a1, a2, a3, a4, a5, a6, a7, a8; };

// Inline-asm load: opaque to the backend's scheduler & waitcnt pass, so the
// prefetch distance is structural, not a compiler choice.
#define GLOAD(dst, ptr, OFF)                                              \
    asm volatile("global_load_dwordx4 %0, %1, off offset:" #OFF          \
                 : "=v"(dst) : "v"(ptr))

#define ISSUE_ROW(S, tp, apn) do {                                        \
    GLOAD((S).t0, (tp), 0);   GLOAD((S).t1, (tp), 16);                    \
    GLOAD((S).t2, (tp), 32);                                              \
    GLOAD((S).a0, (apn), 0);  GLOAD((S).a1, (apn), 16);                   \
    GLOAD((S).a2, (apn), 32); GLOAD((S).a3, (apn), 48);                   \
    GLOAD((S).a4, (apn), 64); GLOAD((S).a5, (apn), 80);                   \
    GLOAD((S).a6, (apn), 96); GLOAD((S).a7, (apn), 112);                  \
    GLOAD((S).a8, (apn), 128);                                            \
} while (0)

#define WAITV(N) asm volatile("s_waitcnt vmcnt(" #N ")" ::: "memory")

#define UNPACK4(arr, off, v) do {                                         \
    arr[(off)+0] = (v)[0]; arr[(off)+1] = (v)[1];                         \
    arr[(off)+2] = (v)[2]; arr[(off)+3] = (v)[3]; } while (0)

// One row step: wait for this row's data (issued 2 rows ago), issue the row
// two ahead, fence, compute. vmcnt trace (12 loads/row): before wait the
// outstanding set is {r, r+1} = 24; vmcnt(12) retires row r (in-order);
// issue(r+2) restores 24. Steady-state prefetch distance = 2 compute-rows
// (~1000+ cy) > HBM miss latency (~900 cy).
#define ROW_STEP(rr, S_CUR, S_DST)                                        \
    WAITV(12);                                                            \
    __builtin_amdgcn_sched_barrier(0);                                    \
    ISSUE_ROW(S_DST, tN, aN); tN += Mc * 3; aN += Mc * 9;                 \
    __builtin_amdgcn_sched_barrier(0);                                    \
    compute_row((rr), S_CUR)

__global__ __launch_bounds__(64, 1)
void ForwardDecoder_kernel(const float* __restrict__ theta,
                           const float* __restrict__ A,
                           float* __restrict__ out) {
    const int b = blockIdx.x;
    const int L = threadIdx.x;          // 0..63; owns grid cols 4L+1..4L+4

    // Per-lane base pointers (data row 0, data cols 4L..4L+3).
    const float* thp = theta + ((size_t)b * Nr * Mc + 4 * L) * 3;
    const float* ap  = A     + ((size_t)b * Nr * Mc + 4 * L) * 9;

    // Prev-row V for own grid cols 4L+1..4L+4.
    float pv0[4], pv1[4], pv2[4];
    #pragma unroll
    for (int j = 0; j < 4; ++j) { pv0[j] = NEG_INF; pv1[j] = NEG_INF; pv2[j] = NEG_INF; }

    auto compute_row = [&](int r, const RowRegs& S) {
        float Th[12], Aa[36];
        UNPACK4(Th, 0, S.t0);  UNPACK4(Th, 4, S.t1);  UNPACK4(Th, 8, S.t2);
        UNPACK4(Aa, 0, S.a0);  UNPACK4(Aa, 4, S.a1);  UNPACK4(Aa, 8, S.a2);
        UNPACK4(Aa,12, S.a3);  UNPACK4(Aa,16, S.a4);  UNPACK4(Aa,20, S.a5);
        UNPACK4(Aa,24, S.a6);  UNPACK4(Aa,28, S.a7);  UNPACK4(Aa,32, S.a8);

        // Prev-row left boundary (grid col 4L) from lane L-1's last column.
        float bl0 = dppf<0x138>(pv0[3]);        // wave_shr1 == shfl_up(x,1)
        float bl1 = dppf<0x138>(pv1[3]);
        float bl2 = dppf<0x138>(pv2[3]);
        if (L == 0) {
            float bv = (r == 0) ? 0.0f : NEG_INF;   // V[r][0]
            bl0 = bv; bl1 = bv; bl2 = bv;
        }

        // States 0 (diag) and 1 (up) for the 4 owned columns — all parallel.
        float v0[4], v1[4];
        #pragma unroll
        for (int j = 0; j < 4; ++j) {
            float d0 = (j == 0) ? bl0 : pv0[j-1];
            float d1 = (j == 0) ? bl1 : pv1[j-1];
            float d2 = (j == 0) ? bl2 : pv2[j-1];
            const float* aj = &Aa[9*j];
            v0[j] = Th[3*j+0] + lse3(d0 + aj[0], d1 + aj[1], d2 + aj[2]);
            v1[j] = Th[3*j+1] + lse3(pv0[j] + aj[3], pv1[j] + aj[4], pv2[j] + aj[5]);
        }

        // Current-row left-neighbor v0/v1 for the state-2 'b' terms.
        float lx0 = dppf<0x138>(v0[3]);
        float lx1 = dppf<0x138>(v1[3]);

        // Per-column affine map f_c(x) = lae2(a_c + x, b_c); in-lane prefixes.
        float pa[4], pb[4];
        #pragma unroll
        for (int j = 0; j < 4; ++j) {
            float n0 = (j == 0) ? lx0 : v0[j-1];
            float n1 = (j == 0) ? lx1 : v1[j-1];
            if (L == 0 && j == 0) { n0 = NEG_INF; n1 = NEG_INF; }  // V[r+1][0]
            const float* aj = &Aa[9*j];
            float a  = Th[3*j+2] + aj[8];
            float bb = Th[3*j+2] + lae2(n0 + aj[6], n1 + aj[7]);
            if (j == 0) { pa[0] = a; pb[0] = bb; }
            else        { pa[j] = pa[j-1] + a; pb[j] = lae2(a + pb[j-1], bb); }
        }

        // Wave-inclusive scan of lane composites, DPP network:
        // row_shr 1/2/4/8 (within-16 Kogge-Stone), then bcast15 merges rows
        // 1,3 (lanes 16-31 <- lane15, 48-63 <- lane47), bcast31 merges lanes
        // 32-63 <- lane31. combine(cur=(SA,SB), earlier=(ao,bo)).
        float SA = pa[3], SB = pb[3];
        const int l16 = L & 15;
        { float ao = dppf<0x111>(SA), bo = dppf<0x111>(SB);
          if (l16 >= 1) { SB = lae2(SA + bo, SB); SA += ao; } }
        { float ao = dppf<0x112>(SA), bo = dppf<0x112>(SB);
          if (l16 >= 2) { SB = lae2(SA + bo, SB); SA += ao; } }
        { float ao = dppf<0x114>(SA), bo = dppf<0x114>(SB);
          if (l16 >= 4) { SB = lae2(SA + bo, SB); SA += ao; } }
        { float ao = dppf<0x118>(SA), bo = dppf<0x118>(SB);
          if (l16 >= 8) { SB = lae2(SA + bo, SB); SA += ao; } }
        { float ao = dppf<0x142>(SA), bo = dppf<0x142>(SB);
          if (L & 16)  { SB = lae2(SA + bo, SB); SA += ao; } }
        { float ao = dppf<0x143>(SA), bo = dppf<0x143>(SB);
          if (L >= 32) { SB = lae2(SA + bo, SB); SA += ao; } }

        // Exclusive carry -> v2 entering this lane (value at grid col 4L).
        float eA = dppf<0x138>(SA);
        float eB = dppf<0x138>(SB);
        float xL = (L == 0) ? NEG_INF : lae2(eA + NEG_INF, eB);

        float v2[4];
        #pragma unroll
        for (int j = 0; j < 4; ++j) v2[j] = lae2(pa[j] + xL, pb[j]);

        // Commit as prev row.
        #pragma unroll
        for (int j = 0; j < 4; ++j) { pv0[j] = v0[j]; pv1[j] = v1[j]; pv2[j] = v2[j]; }

        if (r == Nr - 1 && L == 63) {
            out[b] = lse3(v0[3], v1[3], v2[3]);   // V[N][M]
        }
    };

    // ---- Prefetch pipeline: 4 register sets, distance 2 rows. ----
    RowRegs S0, S1, S2, S3;
    const float* tN = thp;   // next row to issue
    const float* aN = ap;

    ISSUE_ROW(S0, tN, aN); tN += Mc * 3; aN += Mc * 9;   // row 0
    ISSUE_ROW(S1, tN, aN); tN += Mc * 3; aN += Mc * 9;   // row 1

    // Main loop: rows 0..251 (63 x 4), each row issues row+2 (rows 2..253).
    for (int r = 0; r < Nr - 4; r += 4) {
        ROW_STEP(r + 0, S0, S2);
        ROW_STEP(r + 1, S1, S3);
        ROW_STEP(r + 2, S2, S0);
        ROW_STEP(r + 3, S3, S1);
    }

    // Tail rows 252..255: issue rows 254,255; final row drains with vmcnt(0).
    WAITV(12); __builtin_amdgcn_sched_barrier(0);
    ISSUE_ROW(S2, tN, aN); tN += Mc * 3; aN += Mc * 9;   // row 254
    __builtin_amdgcn_sched_barrier(0);
    compute_row(Nr - 4, S0);

    WAITV(12); __builtin_amdgcn_sched_barrier(0);
    ISSUE_ROW(S3, tN, aN);                               // row 255
    __builtin_amdgcn_sched_barrier(0);
    compute_row(Nr - 3, S1);

    WAITV(12); __builtin_amdgcn_sched_barrier(0);
    compute_row(Nr - 2, S2);

    WAITV(0);  __builtin_amdgcn_sched_barrier(0);
    compute_row(Nr - 1, S3);
}

extern "C" void kernel_launch(void* const* d_in, const int* in_sizes, int n_in,
                              void* d_out, int out_size, void* d_ws, size_t ws_size,
                              hipStream_t stream) {
    const float* theta = (const float*)d_in[0];
    const float* A     = (const float*)d_in[1];
    // d_in[2] = pos is fixed to [(-1,-1),(-1,0),(0,-1)] -> idx=[0,1,2], hardcoded.
    float* out = (float*)d_out;

    const int B = in_sizes[0] / (Nr * Mc * 3);   // 128
    ForwardDecoder_kernel<<<B, 64, 0, stream>>>(theta, A, out);
}